// Round 2
// baseline (204.006 us; speedup 1.0000x reference)
//
#include <hip/hip_runtime.h>
#include <hip/hip_bf16.h>

typedef __bf16 bf16x8 __attribute__((ext_vector_type(8)));
typedef float f32x4 __attribute__((ext_vector_type(4)));

// Problem constants
#define SEQ   2048
#define NHEAD 12
#define NBH   24          // B * NHEAD
#define NTOK  4096        // B * SEQ
#define CDIM  768
// scale folded into Q at QKV epilogue: head_dim^-0.5 * log2(e)  (softmax via exp2)
#define QSCALE 0.18033688011112042f

__device__ __forceinline__ unsigned short f2bf(float f) {
  unsigned int u = __builtin_bit_cast(unsigned int, f);
  u += 0x7FFFu + ((u >> 16) & 1u);          // round-to-nearest-even
  return (unsigned short)(u >> 16);
}

__device__ __forceinline__ unsigned int packbf2(float a, float b) {
  return ((unsigned int)f2bf(b) << 16) | (unsigned int)f2bf(a);
}

// ---------------------------------------------------------------- cvt fp32->bf16
__global__ __launch_bounds__(256) void cvt_kernel(const float4* __restrict__ src,
                                                  ushort4* __restrict__ dst, int n4) {
  int i = blockIdx.x * 256 + threadIdx.x;
  if (i < n4) {
    float4 v = src[i];
    ushort4 r;
    r.x = f2bf(v.x); r.y = f2bf(v.y); r.z = f2bf(v.z); r.w = f2bf(v.w);
    dst[i] = r;
  }
}

// ---------------------------------------------------------------- GEMM  C = X @ W^T (+bias)
// X: [M=4096][768] bf16 row-major, W: [BN-tiles of rows][768] bf16 row-major.
// MODE 0: qkv epilogue -> scatter Q(scaled)/K/[Vt transposed], MODE 1: plain fp32 out + bias.
template <int BN, int MODE>
__global__ __launch_bounds__(256) void gemm_kernel(const unsigned short* __restrict__ X,
                                                   const unsigned short* __restrict__ W,
                                                   const float* __restrict__ bias,
                                                   unsigned short* __restrict__ Qb,
                                                   unsigned short* __restrict__ Kb,
                                                   unsigned short* __restrict__ Vtb,
                                                   float* __restrict__ Out) {
  constexpr int K = 768, BM = 128, BK = 64;
  constexpr int WN = BN / 2;      // wave col extent (2x2 wave grid)
  constexpr int NT = WN / 16;     // col 16-tiles per wave
  __shared__ __align__(16) unsigned short Xs[BM * BK];
  __shared__ __align__(16) unsigned short Ws[BN * BK];

  const int tid = threadIdx.x;
  const int w = tid >> 6, lane = tid & 63, quad = lane >> 4, m16 = lane & 15;
  const int wm = w & 1, wn = w >> 1;
  const int row0 = blockIdx.y * BM, col0 = blockIdx.x * BN;

  f32x4 acc[4][NT];
#pragma unroll
  for (int mt = 0; mt < 4; ++mt)
#pragma unroll
    for (int nt = 0; nt < NT; ++nt) acc[mt][nt] = (f32x4){0.f, 0.f, 0.f, 0.f};

  for (int k0 = 0; k0 < K; k0 += BK) {
    __syncthreads();
    // stage X tile 128x64 (1024 uint4)
#pragma unroll
    for (int j = 0; j < 4; ++j) {
      int e = tid + 256 * j, r = e >> 3, c8 = e & 7;
      uint4 v = *(const uint4*)(X + (size_t)(row0 + r) * 768 + k0 + c8 * 8);
      *(uint4*)(Xs + r * BK + ((c8 ^ (r & 7)) << 3)) = v;   // XOR-swizzled groups of 8
    }
    // stage W tile BNx64
#pragma unroll
    for (int j = 0; j < BN / 32; ++j) {
      int e = tid + 256 * j, r = e >> 3, c8 = e & 7;
      uint4 v = *(const uint4*)(W + (size_t)(col0 + r) * 768 + k0 + c8 * 8);
      *(uint4*)(Ws + r * BK + ((c8 ^ (r & 7)) << 3)) = v;
    }
    __syncthreads();
#pragma unroll
    for (int ks = 0; ks < 2; ++ks) {
      const int sw = ((quad + 4 * ks) ^ (m16 & 7)) << 3;
      bf16x8 a[4], b[NT];
#pragma unroll
      for (int mt = 0; mt < 4; ++mt)
        a[mt] = *(const bf16x8*)(Xs + (wm * 64 + mt * 16 + m16) * BK + sw);
#pragma unroll
      for (int nt = 0; nt < NT; ++nt)
        b[nt] = *(const bf16x8*)(Ws + (wn * WN + nt * 16 + m16) * BK + sw);
#pragma unroll
      for (int mt = 0; mt < 4; ++mt)
#pragma unroll
        for (int nt = 0; nt < NT; ++nt)
          acc[mt][nt] = __builtin_amdgcn_mfma_f32_16x16x32_bf16(a[mt], b[nt], acc[mt][nt], 0, 0, 0);
    }
  }

  // epilogue
#pragma unroll
  for (int mt = 0; mt < 4; ++mt) {
#pragma unroll
    for (int nt = 0; nt < NT; ++nt) {
      const int m0 = row0 + wm * 64 + mt * 16 + quad * 4;   // rows m0..m0+3
      const int c = col0 + wn * WN + nt * 16 + m16;
      const float bia = bias[c];
      f32x4 v = acc[mt][nt];
      if constexpr (MODE == 0) {
        const int bidx = m0 >> 11, ns = m0 & 2047;
        if (c < 1536) {   // Q or K: layout [bh][n][d]
          unsigned short* dst;
          float sc;
          int cc;
          if (c < 768) { cc = c; dst = Qb; sc = QSCALE; }
          else         { cc = c - 768; dst = Kb; sc = 1.0f; }
          const int h = cc >> 6, d = cc & 63;
          unsigned short* p = dst + ((size_t)(bidx * NHEAD + h) * SEQ + ns) * 64 + d;
          p[0]   = f2bf((v[0] + bia) * sc);
          p[64]  = f2bf((v[1] + bia) * sc);
          p[128] = f2bf((v[2] + bia) * sc);
          p[192] = f2bf((v[3] + bia) * sc);
        } else {          // V transposed: [bh][d][n]
          const int cc = c - 1536, h = cc >> 6, d = cc & 63;
          ushort4 pk;
          pk.x = f2bf(v[0] + bia); pk.y = f2bf(v[1] + bia);
          pk.z = f2bf(v[2] + bia); pk.w = f2bf(v[3] + bia);
          *(ushort4*)(Vtb + ((size_t)(bidx * NHEAD + h) * 64 + d) * SEQ + ns) = pk;
        }
      } else {
        float* o = Out + (size_t)m0 * 768 + c;
        o[0]       = v[0] + bia;
        o[768]     = v[1] + bia;
        o[2 * 768] = v[2] + bia;
        o[3 * 768] = v[3] + bia;
      }
    }
  }
}

// ---------------------------------------------------------------- flash attention (transposed scores)
// Per block: one (b,h), 64 query rows; 4 waves x 16 q-rows each. K/V tiles of 128 keys staged in LDS.
// S^T = K.Q^T via MFMA (lane holds fixed q-col -> in-lane softmax stats), O^T = Vt.P^T.
__global__ __launch_bounds__(256) void attn_kernel(const unsigned short* __restrict__ Qb,
                                                   const unsigned short* __restrict__ Kb,
                                                   const unsigned short* __restrict__ Vtb,
                                                   unsigned short* __restrict__ Ab) {
  __shared__ __align__(16) unsigned short Ks[128 * 64];
  __shared__ __align__(16) unsigned short Vts[64 * 128];
  __shared__ __align__(16) unsigned short Pts[4][16 * 128];

  const int tid = threadIdx.x;
  const int w = tid >> 6, lane = tid & 63, quad = lane >> 4, m16 = lane & 15;
  const int bh = blockIdx.x % NBH;          // same bh -> blocks 24 apart -> same XCD (24%8==0)
  const int qtile = blockIdx.x / NBH;       // 0..31
  const int bb = bh / NHEAD, h = bh % NHEAD;
  const int q0 = qtile * 64 + w * 16;

  const unsigned short* Qp = Qb + (size_t)bh * SEQ * 64;
  const unsigned short* Kp = Kb + (size_t)bh * SEQ * 64;
  const unsigned short* Vp = Vtb + (size_t)bh * 64 * SEQ;
  unsigned short* Pw = &Pts[w][0];

  // Q fragments (B-operand): lane holds Q[q=m16][d = ks*32 + quad*8 + j]
  bf16x8 qf[2];
#pragma unroll
  for (int ks = 0; ks < 2; ++ks)
    qf[ks] = *(const bf16x8*)(Qp + (size_t)(q0 + m16) * 64 + ks * 32 + quad * 8);

  f32x4 o[4];
#pragma unroll
  for (int dt = 0; dt < 4; ++dt) o[dt] = (f32x4){0.f, 0.f, 0.f, 0.f};
  float m_i = -3.0e38f, l_i = 0.f;

  for (int kt = 0; kt < 16; ++kt) {
    __syncthreads();   // previous tile fully consumed
    // stage K tile [128 keys][64 d]
#pragma unroll
    for (int j = 0; j < 4; ++j) {
      int e = tid + 256 * j, r = e >> 3, c8 = e & 7;
      uint4 v = *(const uint4*)(Kp + (size_t)(kt * 128 + r) * 64 + c8 * 8);
      *(uint4*)(Ks + r * 64 + ((c8 ^ (r & 7)) << 3)) = v;
    }
    // stage V^T tile [64 d][128 keys]
#pragma unroll
    for (int j = 0; j < 4; ++j) {
      int e = tid + 256 * j, d = e >> 4, c8 = e & 15;
      uint4 v = *(const uint4*)(Vp + (size_t)d * SEQ + kt * 128 + c8 * 8);
      *(uint4*)(Vts + d * 128 + ((c8 ^ (d & 15)) << 3)) = v;
    }
    __syncthreads();

    // S^T tiles: st[nt] holds S^T[n = nt*16 + quad*4 + i][q = m16]
    f32x4 st[8];
#pragma unroll
    for (int nt = 0; nt < 8; ++nt) st[nt] = (f32x4){0.f, 0.f, 0.f, 0.f};
#pragma unroll
    for (int ks = 0; ks < 2; ++ks) {
      const int sw = ((quad + 4 * ks) ^ (m16 & 7)) << 3;
#pragma unroll
      for (int nt = 0; nt < 8; ++nt) {
        bf16x8 kf = *(const bf16x8*)(Ks + (nt * 16 + m16) * 64 + sw);
        st[nt] = __builtin_amdgcn_mfma_f32_16x16x32_bf16(kf, qf[ks], st[nt], 0, 0, 0);
      }
    }

    // online softmax along keys (rows of S^T): in-lane over 32 vals + 2 shuffles
    float tmax = fmaxf(fmaxf(st[0][0], st[0][1]), fmaxf(st[0][2], st[0][3]));
#pragma unroll
    for (int nt = 1; nt < 8; ++nt)
      tmax = fmaxf(tmax, fmaxf(fmaxf(st[nt][0], st[nt][1]), fmaxf(st[nt][2], st[nt][3])));
    tmax = fmaxf(tmax, __shfl_xor(tmax, 16));
    tmax = fmaxf(tmax, __shfl_xor(tmax, 32));
    const float mnew = fmaxf(m_i, tmax);
    const float alpha = exp2f(m_i - mnew);
    float ssum = 0.f;
#pragma unroll
    for (int nt = 0; nt < 8; ++nt) {
      float p0 = exp2f(st[nt][0] - mnew);
      float p1 = exp2f(st[nt][1] - mnew);
      float p2 = exp2f(st[nt][2] - mnew);
      float p3 = exp2f(st[nt][3] - mnew);
      ssum += (p0 + p1) + (p2 + p3);
      // P^T store: row q=m16, col n = nt*16 + quad*4 + {0..3}, XOR-swizzled groups
      const int g = 2 * nt + (quad >> 1);
      unsigned short* dst = Pw + m16 * 128 + ((g ^ m16) << 3) + (quad & 1) * 4;
      *(unsigned int*)(dst)     = packbf2(p0, p1);
      *(unsigned int*)(dst + 2) = packbf2(p2, p3);
    }
    ssum += __shfl_xor(ssum, 16);
    ssum += __shfl_xor(ssum, 32);
    l_i = l_i * alpha + ssum;
    m_i = mnew;
#pragma unroll
    for (int dt = 0; dt < 4; ++dt) o[dt] *= alpha;

    // O^T += Vt . P^T
#pragma unroll
    for (int ks = 0; ks < 4; ++ks) {
      const int sw = ((quad + 4 * ks) ^ m16) << 3;
      bf16x8 pf = *(const bf16x8*)(Pw + m16 * 128 + sw);
#pragma unroll
      for (int dt = 0; dt < 4; ++dt) {
        bf16x8 vf = *(const bf16x8*)(Vts + (dt * 16 + m16) * 128 + sw);
        o[dt] = __builtin_amdgcn_mfma_f32_16x16x32_bf16(vf, pf, o[dt], 0, 0, 0);
      }
    }
  }

  const float rl = __builtin_amdgcn_rcpf(l_i);
  const size_t orow = ((size_t)bb * SEQ + q0 + m16) * 768 + h * 64;
#pragma unroll
  for (int dt = 0; dt < 4; ++dt) {
    f32x4 ov = o[dt] * rl;
    ushort4 pk;
    pk.x = f2bf(ov[0]); pk.y = f2bf(ov[1]); pk.z = f2bf(ov[2]); pk.w = f2bf(ov[3]);
    *(ushort4*)(Ab + orow + dt * 16 + quad * 4) = pk;
  }
}

// ---------------------------------------------------------------- launch
extern "C" void kernel_launch(void* const* d_in, const int* in_sizes, int n_in,
                              void* d_out, int out_size, void* d_ws, size_t ws_size,
                              hipStream_t stream) {
  const float* x      = (const float*)d_in[0];   // [2,2048,768]
  const float* qkv_w  = (const float*)d_in[1];   // [2304,768]
  const float* qkv_b  = (const float*)d_in[2];   // [2304]
  const float* proj_w = (const float*)d_in[3];   // [768,768]
  const float* proj_b = (const float*)d_in[4];   // [768]
  float* out = (float*)d_out;

  unsigned short* xb  = (unsigned short*)d_ws;        // 3145728
  unsigned short* wqb = xb + 3145728;                 // 1769472
  unsigned short* wpb = wqb + 1769472;                // 589824
  unsigned short* Qb  = wpb + 589824;                 // 3145728 (scaled by QSCALE)
  unsigned short* Kb  = Qb + 3145728;                 // 3145728
  unsigned short* Vtb = Kb + 3145728;                 // 3145728  [bh][d][n]
  unsigned short* Ab  = Vtb + 3145728;                // 3145728  attn out bf16 [tok][768]

  cvt_kernel<<<3072, 256, 0, stream>>>((const float4*)x, (ushort4*)xb, 786432);
  cvt_kernel<<<1728, 256, 0, stream>>>((const float4*)qkv_w, (ushort4*)wqb, 442368);
  cvt_kernel<<<576, 256, 0, stream>>>((const float4*)proj_w, (ushort4*)wpb, 147456);

  gemm_kernel<128, 0><<<dim3(18, 32), 256, 0, stream>>>(xb, wqb, qkv_b, Qb, Kb, Vtb, nullptr);
  attn_kernel<<<768, 256, 0, stream>>>(Qb, Kb, Vtb, Ab);
  gemm_kernel<64, 1><<<dim3(12, 32), 256, 0, stream>>>(Ab, wpb, proj_b, nullptr, nullptr, nullptr, out);
}

// Round 3
// 178.414 us; speedup vs baseline: 1.1434x; 1.1434x over previous
//
#include <hip/hip_runtime.h>
#include <hip/hip_bf16.h>

typedef __bf16 bf16x8 __attribute__((ext_vector_type(8)));
typedef float f32x4 __attribute__((ext_vector_type(4)));
typedef float f32x16 __attribute__((ext_vector_type(16)));

#define SEQ   2048
#define NHEAD 12
#define NBH   24
#define QSCALE 0.18033688011112042f   // head_dim^-0.5 * log2(e)

__device__ __forceinline__ unsigned short f2bf(float f) {
  unsigned int u = __builtin_bit_cast(unsigned int, f);
  u += 0x7FFFu + ((u >> 16) & 1u);
  return (unsigned short)(u >> 16);
}
// truncating pack of two f32 -> bf16x2 in one v_perm_b32 (P values only; ~2^-9 bias OK)
__device__ __forceinline__ unsigned int packbf2_trunc(float lo, float hi) {
  return __builtin_amdgcn_perm(__builtin_bit_cast(unsigned int, hi),
                               __builtin_bit_cast(unsigned int, lo), 0x07060302u);
}

// ---------------------------------------------------------------- fused cvt fp32->bf16 (x, qkv_w, proj_w)
#define NX4  786432
#define NW14 442368
#define NW24 147456
__global__ __launch_bounds__(256) void cvt3_kernel(const float4* __restrict__ x,
                                                   const float4* __restrict__ w1,
                                                   const float4* __restrict__ w2,
                                                   ushort4* __restrict__ xo,
                                                   ushort4* __restrict__ w1o,
                                                   ushort4* __restrict__ w2o) {
  int i = blockIdx.x * 256 + threadIdx.x;
  const float4* s;
  ushort4* d;
  int j = i;
  if (i < NX4)               { s = x;  d = xo; }
  else if (i < NX4 + NW14)   { s = w1; d = w1o; j = i - NX4; }
  else                       { s = w2; d = w2o; j = i - (NX4 + NW14); }
  float4 v = s[j];
  ushort4 r;
  r.x = f2bf(v.x); r.y = f2bf(v.y); r.z = f2bf(v.z); r.w = f2bf(v.w);
  d[j] = r;
}

// ---------------------------------------------------------------- GEMM  C = X @ W^T (+bias)
template <int BM, int BN, int MODE>
__global__ __launch_bounds__(256) void gemm_kernel(const unsigned short* __restrict__ X,
                                                   const unsigned short* __restrict__ W,
                                                   const float* __restrict__ bias,
                                                   unsigned short* __restrict__ Qb,
                                                   unsigned short* __restrict__ Kb,
                                                   unsigned short* __restrict__ Vtb,
                                                   float* __restrict__ Out) {
  constexpr int K = 768, BK = 64;
  constexpr int WM = BM / 2, WN = BN / 2;
  constexpr int MT = WM / 16, NT = WN / 16;
  __shared__ __align__(16) unsigned short Xs[BM * BK];
  __shared__ __align__(16) unsigned short Ws[BN * BK];

  const int tid = threadIdx.x;
  const int w = tid >> 6, lane = tid & 63, quad = lane >> 4, m16 = lane & 15;
  const int wm = w & 1, wn = w >> 1;
  const int row0 = blockIdx.y * BM, col0 = blockIdx.x * BN;

  f32x4 acc[MT][NT];
#pragma unroll
  for (int mt = 0; mt < MT; ++mt)
#pragma unroll
    for (int nt = 0; nt < NT; ++nt) acc[mt][nt] = (f32x4){0.f, 0.f, 0.f, 0.f};

  for (int k0 = 0; k0 < K; k0 += BK) {
    __syncthreads();
#pragma unroll
    for (int j = 0; j < BM / 32; ++j) {
      int e = tid + 256 * j, r = e >> 3, c8 = e & 7;
      uint4 v = *(const uint4*)(X + (size_t)(row0 + r) * 768 + k0 + c8 * 8);
      *(uint4*)(Xs + r * BK + ((c8 ^ (r & 7)) << 3)) = v;
    }
#pragma unroll
    for (int j = 0; j < BN / 32; ++j) {
      int e = tid + 256 * j, r = e >> 3, c8 = e & 7;
      uint4 v = *(const uint4*)(W + (size_t)(col0 + r) * 768 + k0 + c8 * 8);
      *(uint4*)(Ws + r * BK + ((c8 ^ (r & 7)) << 3)) = v;
    }
    __syncthreads();
#pragma unroll
    for (int ks = 0; ks < 2; ++ks) {
      const int sw = ((quad + 4 * ks) ^ (m16 & 7)) << 3;
      bf16x8 a[MT], b[NT];
#pragma unroll
      for (int mt = 0; mt < MT; ++mt)
        a[mt] = *(const bf16x8*)(Xs + (wm * WM + mt * 16 + m16) * BK + sw);
#pragma unroll
      for (int nt = 0; nt < NT; ++nt)
        b[nt] = *(const bf16x8*)(Ws + (wn * WN + nt * 16 + m16) * BK + sw);
#pragma unroll
      for (int mt = 0; mt < MT; ++mt)
#pragma unroll
        for (int nt = 0; nt < NT; ++nt)
          acc[mt][nt] = __builtin_amdgcn_mfma_f32_16x16x32_bf16(a[mt], b[nt], acc[mt][nt], 0, 0, 0);
    }
  }

#pragma unroll
  for (int mt = 0; mt < MT; ++mt) {
#pragma unroll
    for (int nt = 0; nt < NT; ++nt) {
      const int m0 = row0 + wm * WM + mt * 16 + quad * 4;
      const int c = col0 + wn * WN + nt * 16 + m16;
      const float bia = bias[c];
      f32x4 v = acc[mt][nt];
      if constexpr (MODE == 0) {
        const int bidx = m0 >> 11, ns = m0 & 2047;
        if (c < 1536) {   // Q or K: [bh][n][d]
          unsigned short* dst;
          float sc;
          int cc;
          if (c < 768) { cc = c; dst = Qb; sc = QSCALE; }
          else         { cc = c - 768; dst = Kb; sc = 1.0f; }
          const int h = cc >> 6, d = cc & 63;
          unsigned short* p = dst + ((size_t)(bidx * NHEAD + h) * SEQ + ns) * 64 + d;
          p[0]   = f2bf((v[0] + bia) * sc);
          p[64]  = f2bf((v[1] + bia) * sc);
          p[128] = f2bf((v[2] + bia) * sc);
          p[192] = f2bf((v[3] + bia) * sc);
        } else {          // V transposed: [bh][d][n]
          const int cc = c - 1536, h = cc >> 6, d = cc & 63;
          ushort4 pk;
          pk.x = f2bf(v[0] + bia); pk.y = f2bf(v[1] + bia);
          pk.z = f2bf(v[2] + bia); pk.w = f2bf(v[3] + bia);
          *(ushort4*)(Vtb + ((size_t)(bidx * NHEAD + h) * 64 + d) * SEQ + ns) = pk;
        }
      } else {
        float* o = Out + (size_t)m0 * 768 + c;
        o[0]       = v[0] + bia;
        o[768]     = v[1] + bia;
        o[2 * 768] = v[2] + bia;
        o[3 * 768] = v[3] + bia;
      }
    }
  }
}

// ---------------------------------------------------------------- flash attention, 32x32 MFMA
// 384 blocks = 24 bh x 16 q-tiles(128). 4 waves x 32 q. S^T = K.Q^T (C-layout: lane = fixed q col).
// P stays in registers: Vt staged with key-bits2<->3 swapped so P's C-layout IS the PV B-operand.
#define VPAD 136   // 128 + 8 shorts: rows start at distinct banks (17*16B)
__global__ __launch_bounds__(256, 2) void attn_kernel(const unsigned short* __restrict__ Qb,
                                                      const unsigned short* __restrict__ Kb,
                                                      const unsigned short* __restrict__ Vtb,
                                                      unsigned short* __restrict__ Ab) {
  __shared__ __align__(16) unsigned short Ks[128 * 64];
  __shared__ __align__(16) unsigned short Vts[64 * VPAD];

  const int tid = threadIdx.x;
  const int w = tid >> 6, lane = tid & 63, hi = lane >> 5, l32 = lane & 31;
  const int bh = blockIdx.x % NBH, qt = blockIdx.x / NBH;
  const int bb = bh / NHEAD, h = bh % NHEAD;
  const int q0 = qt * 128 + w * 32;

  const unsigned short* Qp = Qb + (size_t)bh * SEQ * 64;
  const unsigned short* Kp = Kb + (size_t)bh * SEQ * 64;
  const unsigned short* Vp = Vtb + (size_t)bh * 64 * SEQ;

  // Q B-frags: lane holds Q[q0+l32][dc*16 + hi*8 + j]
  bf16x8 qf[4];
#pragma unroll
  for (int dc = 0; dc < 4; ++dc)
    qf[dc] = *(const bf16x8*)(Qp + (size_t)(q0 + l32) * 64 + dc * 16 + hi * 8);

  f32x16 o[2] = {};
  float m_i = -3.0e38f, l_i = 0.f;

  for (int kt = 0; kt < 16; ++kt) {
    __syncthreads();
    // stage K tile [128 keys][64 d], XOR-swizzled 16B groups
#pragma unroll
    for (int j = 0; j < 4; ++j) {
      int e = tid + 256 * j, r = e >> 3, c8 = e & 7;
      uint4 v = *(const uint4*)(Kp + (size_t)(kt * 128 + r) * 64 + c8 * 8);
      *(uint4*)(Ks + r * 64 + ((c8 ^ (r & 7)) << 3)) = v;
    }
    // stage V^T tile [64 d][128 keys], key bits 2<->3 swapped (slot order), padded rows
#pragma unroll
    for (int j = 0; j < 4; ++j) {
      int e = tid + 256 * j, d = e >> 4, c8 = e & 15;
      uint4 v = *(const uint4*)(Vp + (size_t)d * SEQ + kt * 128 + c8 * 8);
      unsigned short* row = Vts + d * VPAD + (c8 >> 1) * 16 + (c8 & 1) * 4;
      *(uint2*)(row)     = make_uint2(v.x, v.y);   // keys c8*8 .. +3  -> slots base..+3
      *(uint2*)(row + 8) = make_uint2(v.z, v.w);   // keys c8*8+4..+7 -> slots base+8..+11
    }
    __syncthreads();

    // S^T[128][32]: 4 key-tiles of 32, each 16 regs (row=key: (r&3)+8*(r>>2)+4*hi, col=q=l32)
    f32x16 st[4];
#pragma unroll
    for (int t32 = 0; t32 < 4; ++t32) {
      f32x16 s = {};
#pragma unroll
      for (int dc = 0; dc < 4; ++dc) {
        bf16x8 kf = *(const bf16x8*)(Ks + (t32 * 32 + l32) * 64 + ((((dc << 1) | hi) ^ (l32 & 7)) << 3));
        s = __builtin_amdgcn_mfma_f32_32x32x16_bf16(kf, qf[dc], s, 0, 0, 0);
      }
      st[t32] = s;
    }

    // online softmax: lane holds 64 key-scores of its q; partner lane (^32) has the other 64
    float tmax = st[0][0];
#pragma unroll
    for (int t32 = 0; t32 < 4; ++t32)
#pragma unroll
      for (int e = 0; e < 16; ++e) tmax = fmaxf(tmax, st[t32][e]);
    tmax = fmaxf(tmax, __shfl_xor(tmax, 32));
    const float mnew = fmaxf(m_i, tmax);
    const float alpha = exp2f(m_i - mnew);
    float ssum = 0.f;
    unsigned int pf[4][8];
#pragma unroll
    for (int t32 = 0; t32 < 4; ++t32) {
      float pv[16];
#pragma unroll
      for (int e = 0; e < 16; ++e) { pv[e] = exp2f(st[t32][e] - mnew); ssum += pv[e]; }
#pragma unroll
      for (int e2 = 0; e2 < 8; ++e2)
        pf[t32][e2] = packbf2_trunc(pv[2 * e2], pv[2 * e2 + 1]);
    }
    ssum += __shfl_xor(ssum, 32);
    l_i = l_i * alpha + ssum;
    m_i = mnew;
    o[0] *= alpha;
    o[1] *= alpha;

    // O^T += Vt . P^T : chunk (t32,hh) of 16 keys; B-frag = st elements hh*8..+7 (packed)
#pragma unroll
    for (int t32 = 0; t32 < 4; ++t32) {
#pragma unroll
      for (int hh = 0; hh < 2; ++hh) {
        bf16x8 pfrag = __builtin_bit_cast(bf16x8,
            make_uint4(pf[t32][hh * 4], pf[t32][hh * 4 + 1], pf[t32][hh * 4 + 2], pf[t32][hh * 4 + 3]));
        const int slotbase = t32 * 32 + hh * 16 + hi * 8;
#pragma unroll
        for (int dt = 0; dt < 2; ++dt) {
          bf16x8 vf = *(const bf16x8*)(Vts + (dt * 32 + l32) * VPAD + slotbase);
          o[dt] = __builtin_amdgcn_mfma_f32_32x32x16_bf16(vf, pfrag, o[dt], 0, 0, 0);
        }
      }
    }
  }

  // epilogue: O^T C-layout -> Ab[token][768] bf16; lane's q = q0 + l32 fixed
  const float rl = __builtin_amdgcn_rcpf(l_i);
  unsigned short* base = Ab + ((size_t)bb * SEQ + q0 + l32) * 768 + h * 64;
#pragma unroll
  for (int dt = 0; dt < 2; ++dt) {
#pragma unroll
    for (int run = 0; run < 4; ++run) {
      ushort4 pk;
      pk.x = f2bf(o[dt][run * 4 + 0] * rl);
      pk.y = f2bf(o[dt][run * 4 + 1] * rl);
      pk.z = f2bf(o[dt][run * 4 + 2] * rl);
      pk.w = f2bf(o[dt][run * 4 + 3] * rl);
      *(ushort4*)(base + dt * 32 + run * 8 + hi * 4) = pk;
    }
  }
}

// ---------------------------------------------------------------- launch
extern "C" void kernel_launch(void* const* d_in, const int* in_sizes, int n_in,
                              void* d_out, int out_size, void* d_ws, size_t ws_size,
                              hipStream_t stream) {
  const float* x      = (const float*)d_in[0];
  const float* qkv_w  = (const float*)d_in[1];
  const float* qkv_b  = (const float*)d_in[2];
  const float* proj_w = (const float*)d_in[3];
  const float* proj_b = (const float*)d_in[4];
  float* out = (float*)d_out;

  unsigned short* xb  = (unsigned short*)d_ws;
  unsigned short* wqb = xb + 3145728;
  unsigned short* wpb = wqb + 1769472;
  unsigned short* Qb  = wpb + 589824;
  unsigned short* Kb  = Qb + 3145728;
  unsigned short* Vtb = Kb + 3145728;
  unsigned short* Ab  = Vtb + 3145728;

  cvt3_kernel<<<5376, 256, 0, stream>>>((const float4*)x, (const float4*)qkv_w, (const float4*)proj_w,
                                        (ushort4*)xb, (ushort4*)wqb, (ushort4*)wpb);
  gemm_kernel<128, 96, 0><<<dim3(24, 32), 256, 0, stream>>>(xb, wqb, qkv_b, Qb, Kb, Vtb, nullptr);
  attn_kernel<<<384, 256, 0, stream>>>(Qb, Kb, Vtb, Ab);
  gemm_kernel<64, 96, 1><<<dim3(8, 64), 256, 0, stream>>>(Ab, wpb, proj_b, nullptr, nullptr, nullptr, out);
}

// Round 4
// 170.935 us; speedup vs baseline: 1.1935x; 1.0438x over previous
//
#include <hip/hip_runtime.h>
#include <hip/hip_bf16.h>

typedef __bf16 bf16x8 __attribute__((ext_vector_type(8)));
typedef float f32x4 __attribute__((ext_vector_type(4)));
typedef float f32x16 __attribute__((ext_vector_type(16)));

#define SEQ   2048
#define NHEAD 12
#define NBH   24
#define QSCALE 0.18033688011112042f   // head_dim^-0.5 * log2(e)

// async global->LDS 16B copy; lds dest must be wave-uniform base + lane*16
#define CP16(g, l) __builtin_amdgcn_global_load_lds( \
    (const __attribute__((address_space(1))) unsigned int*)(g), \
    (__attribute__((address_space(3))) unsigned int*)(l), 16, 0, 0)

__device__ __forceinline__ unsigned short f2bf(float f) {
  unsigned int u = __builtin_bit_cast(unsigned int, f);
  u += 0x7FFFu + ((u >> 16) & 1u);
  return (unsigned short)(u >> 16);
}
// truncating pack of two f32 -> bf16x2 in one v_perm_b32 (P in [0,1]; ~2^-9 bias OK)
__device__ __forceinline__ unsigned int packbf2_trunc(float lo, float hi) {
  return __builtin_amdgcn_perm(__builtin_bit_cast(unsigned int, hi),
                               __builtin_bit_cast(unsigned int, lo), 0x07060302u);
}

// ---------------------------------------------------------------- fused cvt fp32->bf16
#define NX4  786432
#define NW14 442368
__global__ __launch_bounds__(256) void cvt3_kernel(const float4* __restrict__ x,
                                                   const float4* __restrict__ w1,
                                                   const float4* __restrict__ w2,
                                                   ushort4* __restrict__ xo,
                                                   ushort4* __restrict__ w1o,
                                                   ushort4* __restrict__ w2o) {
  int i = blockIdx.x * 256 + threadIdx.x;
  const float4* s;
  ushort4* d;
  int j = i;
  if (i < NX4)               { s = x;  d = xo; }
  else if (i < NX4 + NW14)   { s = w1; d = w1o; j = i - NX4; }
  else                       { s = w2; d = w2o; j = i - (NX4 + NW14); }
  float4 v = s[j];
  ushort4 r;
  r.x = f2bf(v.x); r.y = f2bf(v.y); r.z = f2bf(v.z); r.w = f2bf(v.w);
  d[j] = r;
}

// ---------------------------------------------------------------- GEMM  C = X @ W^T (+bias)
// async staging: LDS slot e holds global chunk (c8 ^ (r&7)) of row r -> reads use XOR swizzle.
template <int BM, int BN, int MODE>
__global__ __launch_bounds__(256) void gemm_kernel(const unsigned short* __restrict__ X,
                                                   const unsigned short* __restrict__ W,
                                                   const float* __restrict__ bias,
                                                   unsigned short* __restrict__ Qb,
                                                   unsigned short* __restrict__ Kb,
                                                   unsigned short* __restrict__ Vtb,
                                                   float* __restrict__ Out) {
  constexpr int K = 768, BK = 64;
  constexpr int WM = BM / 2, WN = BN / 2;
  constexpr int MT = WM / 16, NT = WN / 16;
  __shared__ __align__(16) unsigned short Xs[BM * BK];
  __shared__ __align__(16) unsigned short Ws[BN * BK];

  const int tid = threadIdx.x;
  const int w = tid >> 6, lane = tid & 63, quad = lane >> 4, m16 = lane & 15;
  const int wm = w & 1, wn = w >> 1;
  const int row0 = blockIdx.y * BM, col0 = blockIdx.x * BN;

  f32x4 acc[MT][NT];
#pragma unroll
  for (int mt = 0; mt < MT; ++mt)
#pragma unroll
    for (int nt = 0; nt < NT; ++nt) acc[mt][nt] = (f32x4){0.f, 0.f, 0.f, 0.f};

  for (int k0 = 0; k0 < K; k0 += BK) {
    __syncthreads();
#pragma unroll
    for (int j = 0; j < BM / 32; ++j) {
      int e = tid + 256 * j, r = e >> 3, c8 = e & 7;
      CP16(X + (size_t)(row0 + r) * 768 + k0 + ((c8 ^ (r & 7)) << 3), Xs + e * 8);
    }
#pragma unroll
    for (int j = 0; j < BN / 32; ++j) {
      int e = tid + 256 * j, r = e >> 3, c8 = e & 7;
      CP16(W + (size_t)(col0 + r) * 768 + k0 + ((c8 ^ (r & 7)) << 3), Ws + e * 8);
    }
    __syncthreads();
#pragma unroll
    for (int ks = 0; ks < 2; ++ks) {
      const int sw = ((quad + 4 * ks) ^ (m16 & 7)) << 3;
      bf16x8 a[MT], b[NT];
#pragma unroll
      for (int mt = 0; mt < MT; ++mt)
        a[mt] = *(const bf16x8*)(Xs + (wm * WM + mt * 16 + m16) * BK + sw);
#pragma unroll
      for (int nt = 0; nt < NT; ++nt)
        b[nt] = *(const bf16x8*)(Ws + (wn * WN + nt * 16 + m16) * BK + sw);
#pragma unroll
      for (int mt = 0; mt < MT; ++mt)
#pragma unroll
        for (int nt = 0; nt < NT; ++nt)
          acc[mt][nt] = __builtin_amdgcn_mfma_f32_16x16x32_bf16(a[mt], b[nt], acc[mt][nt], 0, 0, 0);
    }
  }

#pragma unroll
  for (int mt = 0; mt < MT; ++mt) {
#pragma unroll
    for (int nt = 0; nt < NT; ++nt) {
      const int m0 = row0 + wm * WM + mt * 16 + quad * 4;
      const int c = col0 + wn * WN + nt * 16 + m16;
      const float bia = bias[c];
      f32x4 v = acc[mt][nt];
      if constexpr (MODE == 0) {
        const int bidx = m0 >> 11, ns = m0 & 2047;
        if (c < 1536) {   // Q or K: [bh][n][d]
          unsigned short* dst;
          float sc;
          int cc;
          if (c < 768) { cc = c; dst = Qb; sc = QSCALE; }
          else         { cc = c - 768; dst = Kb; sc = 1.0f; }
          const int h = cc >> 6, d = cc & 63;
          unsigned short* p = dst + ((size_t)(bidx * NHEAD + h) * SEQ + ns) * 64 + d;
          p[0]   = f2bf((v[0] + bia) * sc);
          p[64]  = f2bf((v[1] + bia) * sc);
          p[128] = f2bf((v[2] + bia) * sc);
          p[192] = f2bf((v[3] + bia) * sc);
        } else {          // V transposed [bh][d][n], sigma-permuted keys (bits2<->3 of n&15)
          const int cc = c - 1536, h = cc >> 6, d = cc & 63;
          const int ns2 = (ns & ~12) | ((ns & 4) << 1) | ((ns & 8) >> 1);
          ushort4 pk;
          pk.x = f2bf(v[0] + bia); pk.y = f2bf(v[1] + bia);
          pk.z = f2bf(v[2] + bia); pk.w = f2bf(v[3] + bia);
          *(ushort4*)(Vtb + ((size_t)(bidx * NHEAD + h) * 64 + d) * SEQ + ns2) = pk;
        }
      } else {
        float* o = Out + (size_t)m0 * 768 + c;
        o[0]       = v[0] + bia;
        o[768]     = v[1] + bia;
        o[2 * 768] = v[2] + bia;
        o[3 * 768] = v[3] + bia;
      }
    }
  }
}

// ---------------------------------------------------------------- flash attention
// 768 blocks = 24 bh x 32 q-tiles(64); 2 waves x 32 q. 64-key tiles, double-buffered async
// staging, ONE barrier per iter. S^T = K.Q^T; P in registers; O^T = Vt.P^T (Vt sigma-permuted
// in global so P's C-layout IS the PV B-operand).
__global__ __launch_bounds__(128) void attn_kernel(const unsigned short* __restrict__ Qb,
                                                   const unsigned short* __restrict__ Kb,
                                                   const unsigned short* __restrict__ Vtb,
                                                   unsigned short* __restrict__ Ab) {
  __shared__ __align__(16) unsigned short Ks[2][64 * 64];
  __shared__ __align__(16) unsigned short Vts[2][64 * 64];

  const int tid = threadIdx.x;
  const int w = tid >> 6, lane = tid & 63, hi = lane >> 5, l32 = lane & 31;
  const int bh = blockIdx.x % NBH, qt = blockIdx.x / NBH;   // same bh -> same XCD (24%8==0)
  const int bb = bh / NHEAD, h = bh % NHEAD;
  const int q0 = qt * 64 + w * 32;

  const unsigned short* Qp = Qb + (size_t)bh * SEQ * 64;
  const unsigned short* Kp = Kb + (size_t)bh * SEQ * 64;
  const unsigned short* Vp = Vtb + (size_t)bh * 64 * SEQ;

  // Q B-frags: lane holds Q[q0+l32][dc*16 + hi*8 + j]
  bf16x8 qf[4];
#pragma unroll
  for (int dc = 0; dc < 4; ++dc)
    qf[dc] = *(const bf16x8*)(Qp + (size_t)(q0 + l32) * 64 + dc * 16 + hi * 8);

  // prologue: stage tile 0 into buf 0
#pragma unroll
  for (int j = 0; j < 4; ++j) {
    int e = tid + 128 * j, r = e >> 3, c8 = e & 7;
    CP16(Kp + (size_t)r * 64 + ((c8 ^ (r & 7)) << 3), &Ks[0][e * 8]);
    CP16(Vp + (size_t)r * SEQ + ((c8 ^ (r & 7)) << 3), &Vts[0][e * 8]);
  }

  f32x16 o[2] = {};
  float m_i = -3.0e38f, l_i = 0.f;

  for (int kt = 0; kt < 32; ++kt) {
    const int cur = kt & 1;
    __syncthreads();   // drains vmcnt -> buf[cur] ready; all waves done reading buf[1-cur]

    const unsigned short* Kc = Ks[cur];
    const unsigned short* Vc = Vts[cur];
    // frag loads first (ds_read), then prefetch issue, then MFMA/VALU
    bf16x8 kf[2][4], vf[2][4];
#pragma unroll
    for (int t32 = 0; t32 < 2; ++t32)
#pragma unroll
      for (int dc = 0; dc < 4; ++dc)
        kf[t32][dc] = *(const bf16x8*)(Kc + (t32 * 32 + l32) * 64 + ((((dc << 1) | hi) ^ (l32 & 7)) << 3));
#pragma unroll
    for (int dt = 0; dt < 2; ++dt)
#pragma unroll
      for (int cc = 0; cc < 4; ++cc)
        vf[dt][cc] = *(const bf16x8*)(Vc + (dt * 32 + l32) * 64 + ((((cc << 1) | hi) ^ (l32 & 7)) << 3));

    if (kt < 31) {     // async prefetch next tile into buf[1-cur]
      const int kn = kt + 1, nb = 1 - cur;
#pragma unroll
      for (int j = 0; j < 4; ++j) {
        int e = tid + 128 * j, r = e >> 3, c8 = e & 7;
        CP16(Kp + (size_t)(kn * 64 + r) * 64 + ((c8 ^ (r & 7)) << 3), &Ks[nb][e * 8]);
        CP16(Vp + (size_t)r * SEQ + kn * 64 + ((c8 ^ (r & 7)) << 3), &Vts[nb][e * 8]);
      }
    }

    // S^T: st[t32] holds S^T[key = t32*32 + (r&3)+8*(r>>2)+4*hi][q = l32]
    f32x16 st[2];
#pragma unroll
    for (int t32 = 0; t32 < 2; ++t32) {
      f32x16 s = {};
#pragma unroll
      for (int dc = 0; dc < 4; ++dc)
        s = __builtin_amdgcn_mfma_f32_32x32x16_bf16(kf[t32][dc], qf[dc], s, 0, 0, 0);
      st[t32] = s;
    }

    // online softmax: lane holds 32 scores; partner (^32) has the other 32
    float tmax = st[0][0];
#pragma unroll
    for (int t32 = 0; t32 < 2; ++t32)
#pragma unroll
      for (int e = 0; e < 16; ++e) tmax = fmaxf(tmax, st[t32][e]);
    tmax = fmaxf(tmax, __shfl_xor(tmax, 32));
    const float mnew = fmaxf(m_i, tmax);
    const float alpha = __builtin_amdgcn_exp2f(m_i - mnew);
    float ssum = 0.f;
    unsigned int pf[2][8];
#pragma unroll
    for (int t32 = 0; t32 < 2; ++t32) {
      float pv[16];
#pragma unroll
      for (int e = 0; e < 16; ++e) { pv[e] = __builtin_amdgcn_exp2f(st[t32][e] - mnew); ssum += pv[e]; }
#pragma unroll
      for (int e2 = 0; e2 < 8; ++e2)
        pf[t32][e2] = packbf2_trunc(pv[2 * e2], pv[2 * e2 + 1]);
    }
    ssum += __shfl_xor(ssum, 32);
    l_i = l_i * alpha + ssum;
    m_i = mnew;
    o[0] *= alpha;
    o[1] *= alpha;

    // O^T += Vt . P^T
#pragma unroll
    for (int t32 = 0; t32 < 2; ++t32) {
#pragma unroll
      for (int hh = 0; hh < 2; ++hh) {
        bf16x8 pfrag = __builtin_bit_cast(bf16x8,
            make_uint4(pf[t32][hh * 4], pf[t32][hh * 4 + 1], pf[t32][hh * 4 + 2], pf[t32][hh * 4 + 3]));
        const int cc = 2 * t32 + hh;
#pragma unroll
        for (int dt = 0; dt < 2; ++dt)
          o[dt] = __builtin_amdgcn_mfma_f32_32x32x16_bf16(vf[dt][cc], pfrag, o[dt], 0, 0, 0);
      }
    }
  }

  // epilogue: lane's q = q0 + l32; o element d = dt*32 + 8*(r>>2) + 4*hi + (r&3)
  const float rl = __builtin_amdgcn_rcpf(l_i);
  unsigned short* base = Ab + ((size_t)bb * SEQ + q0 + l32) * 768 + h * 64;
#pragma unroll
  for (int dt = 0; dt < 2; ++dt) {
#pragma unroll
    for (int run = 0; run < 4; ++run) {
      ushort4 pk;
      pk.x = f2bf(o[dt][run * 4 + 0] * rl);
      pk.y = f2bf(o[dt][run * 4 + 1] * rl);
      pk.z = f2bf(o[dt][run * 4 + 2] * rl);
      pk.w = f2bf(o[dt][run * 4 + 3] * rl);
      *(ushort4*)(base + dt * 32 + run * 8 + hi * 4) = pk;
    }
  }
}

// ---------------------------------------------------------------- launch
extern "C" void kernel_launch(void* const* d_in, const int* in_sizes, int n_in,
                              void* d_out, int out_size, void* d_ws, size_t ws_size,
                              hipStream_t stream) {
  const float* x      = (const float*)d_in[0];
  const float* qkv_w  = (const float*)d_in[1];
  const float* qkv_b  = (const float*)d_in[2];
  const float* proj_w = (const float*)d_in[3];
  const float* proj_b = (const float*)d_in[4];
  float* out = (float*)d_out;

  unsigned short* xb  = (unsigned short*)d_ws;
  unsigned short* wqb = xb + 3145728;
  unsigned short* wpb = wqb + 1769472;
  unsigned short* Qb  = wpb + 589824;
  unsigned short* Kb  = Qb + 3145728;
  unsigned short* Vtb = Kb + 3145728;
  unsigned short* Ab  = Vtb + 3145728;

  cvt3_kernel<<<5376, 256, 0, stream>>>((const float4*)x, (const float4*)qkv_w, (const float4*)proj_w,
                                        (ushort4*)xb, (ushort4*)wqb, (ushort4*)wpb);
  gemm_kernel<128, 96, 0><<<dim3(24, 32), 256, 0, stream>>>(xb, wqb, qkv_b, Qb, Kb, Vtb, nullptr);
  attn_kernel<<<768, 128, 0, stream>>>(Qb, Kb, Vtb, Ab);
  gemm_kernel<64, 96, 1><<<dim3(8, 64), 256, 0, stream>>>(Ab, wpb, proj_b, nullptr, nullptr, nullptr, out);
}